// Round 1
// baseline (4550.624 us; speedup 1.0000x reference)
//
#include <hip/hip_runtime.h>
#include <hip/hip_bf16.h>

#define NUM_C 1024
#define EMB   512
#define HID   512
#define BATCH 64
#define SEQ   512

// ---------------------------------------------------------------------------
// Swizzle Wh_w [H][H] (pre[j] = sum_k h[k] * Wh_w[j][k]) into a layout where
// thread j reads float4 W4[kb*512 + j] = { Wh_w[j][4kb+0..3] } -> coalesced
// 16B/lane loads in the scan kernel.
// ---------------------------------------------------------------------------
__global__ __launch_bounds__(256) void prep_wsw(const float* __restrict__ Wh,
                                                float* __restrict__ Wsw) {
    int e = blockIdx.x * 256 + threadIdx.x;      // 0 .. 512*512-1
    int j = e >> 9;                               // row of Wh
    int k = e & 511;                              // col of Wh
    Wsw[(size_t)((k >> 2) * 512 + j) * 4 + (k & 3)] = Wh[e];
}

// ---------------------------------------------------------------------------
// C[m][n] = act( sum_k A[m][k]*B[n][k] + bias1[n] + bias2[n] )
// A: [M][K] row-major, B: [N][K] row-major ("NT" gemm), fp32 vector.
// 64x64 tile, 256 threads, each thread 4x4 outputs.
// ---------------------------------------------------------------------------
__global__ __launch_bounds__(256)
void gemm_nt_f32(const float* __restrict__ A, const float* __restrict__ B,
                 float* __restrict__ C, int M, int N, int K,
                 const float* __restrict__ bias1, const float* __restrict__ bias2,
                 int act /*0=none, 1=sigmoid*/) {
    __shared__ float As[64][33];
    __shared__ float Bs[64][33];

    const int n0 = blockIdx.x * 64;
    const int m0 = blockIdx.y * 64;
    const int tid = threadIdx.x;
    const int tx = tid & 15;       // -> n
    const int ty = tid >> 4;       // -> m

    float acc[4][4] = {{0.f}};

    for (int k0 = 0; k0 < K; k0 += 32) {
        // stage 64x32 tiles of A and B: 512 float4 each, 2 per thread
        #pragma unroll
        for (int i = 0; i < 2; ++i) {
            int f   = tid * 2 + i;        // 0..511
            int row = f >> 3;             // 0..63
            int kf  = f & 7;              // 0..7 (float4 index)
            float4 va = *(const float4*)&A[(size_t)(m0 + row) * K + k0 + kf * 4];
            float4 vb = *(const float4*)&B[(size_t)(n0 + row) * K + k0 + kf * 4];
            As[row][kf * 4 + 0] = va.x; As[row][kf * 4 + 1] = va.y;
            As[row][kf * 4 + 2] = va.z; As[row][kf * 4 + 3] = va.w;
            Bs[row][kf * 4 + 0] = vb.x; Bs[row][kf * 4 + 1] = vb.y;
            Bs[row][kf * 4 + 2] = vb.z; Bs[row][kf * 4 + 3] = vb.w;
        }
        __syncthreads();
        #pragma unroll
        for (int kk = 0; kk < 32; ++kk) {
            float a[4], b[4];
            #pragma unroll
            for (int i = 0; i < 4; ++i) a[i] = As[ty * 4 + i][kk];
            #pragma unroll
            for (int j = 0; j < 4; ++j) b[j] = Bs[tx * 4 + j][kk];
            #pragma unroll
            for (int i = 0; i < 4; ++i)
                #pragma unroll
                for (int j = 0; j < 4; ++j)
                    acc[i][j] += a[i] * b[j];
        }
        __syncthreads();
    }

    // epilogue: bias + optional sigmoid, float4 stores
    float bb[4];
    #pragma unroll
    for (int j = 0; j < 4; ++j) {
        int n = n0 + tx * 4 + j;
        float v = 0.f;
        if (bias1) v += bias1[n];
        if (bias2) v += bias2[n];
        bb[j] = v;
    }
    #pragma unroll
    for (int i = 0; i < 4; ++i) {
        size_t m = (size_t)(m0 + ty * 4 + i);
        float4 ov;
        float vv[4];
        #pragma unroll
        for (int j = 0; j < 4; ++j) {
            float v = acc[i][j] + bb[j];
            if (act == 1) v = 1.f / (1.f + expf(-v));
            vv[j] = v;
        }
        ov.x = vv[0]; ov.y = vv[1]; ov.z = vv[2]; ov.w = vv[3];
        *(float4*)&C[m * N + n0 + tx * 4] = ov;
    }
}

// ---------------------------------------------------------------------------
// Liquid time-constant recurrence. One block per batch, h[512] lives in LDS.
// h_new = h + (tanh(h @ Wh^T + xp) - h) / tau ; xp gathered from emb_proj.
// Writes h after every step to hs[b][s][j].
// ---------------------------------------------------------------------------
__global__ __launch_bounds__(512)
void ltc_scan(const int* __restrict__ q, const int* __restrict__ r,
              const float* __restrict__ emb_proj, const float* __restrict__ Wsw,
              const float* __restrict__ tau, float* __restrict__ hs) {
    const int b = blockIdx.x;
    const int j = threadIdx.x;     // 0..511 = output unit

    __shared__ float h_s[512];
    h_s[j] = 0.f;
    const float rtau = 1.0f / tau[j];

    const int* qb = q + b * SEQ;
    const int* rb = r + b * SEQ;
    float* hb = hs + (size_t)b * SEQ * HID;
    const float4* W4 = (const float4*)Wsw;   // W4[kb*512 + j] = Wh[j][4kb..4kb+3]
    __syncthreads();

    for (int s = 0; s < SEQ; ++s) {
        const int idx = qb[s] + NUM_C * rb[s];
        float pre = emb_proj[(size_t)idx * HID + j];   // includes Wx_b + Wh_b

        float p0 = 0.f, p1 = 0.f, p2 = 0.f, p3 = 0.f;
        #pragma unroll 4
        for (int kb = 0; kb < HID / 4; ++kb) {
            const float4 w  = W4[kb * 512 + j];
            const float4 hh = *(const float4*)&h_s[kb * 4];
            p0 += hh.x * w.x;
            p1 += hh.y * w.y;
            p2 += hh.z * w.z;
            p3 += hh.w * w.w;
        }
        pre += (p0 + p1) + (p2 + p3);

        const float hj = h_s[j];
        const float hn = hj + (tanhf(pre) - hj) * rtau;
        __syncthreads();               // all reads of h_s done
        h_s[j] = hn;
        hb[(size_t)s * HID + j] = hn;
        __syncthreads();               // writes visible before next step
    }
}

// ---------------------------------------------------------------------------
extern "C" void kernel_launch(void* const* d_in, const int* in_sizes, int n_in,
                              void* d_out, int out_size, void* d_ws, size_t ws_size,
                              hipStream_t stream) {
    const int*   q    = (const int*)d_in[0];
    const int*   r    = (const int*)d_in[1];
    const float* emb  = (const float*)d_in[2];   // [2048][512]
    const float* Wh_w = (const float*)d_in[3];   // [512][512]
    const float* Wh_b = (const float*)d_in[4];   // [512]
    const float* Wx_w = (const float*)d_in[5];   // [512][512]
    const float* Wx_b = (const float*)d_in[6];   // [512]
    const float* tau  = (const float*)d_in[7];   // [512]
    const float* Wo_w = (const float*)d_in[8];   // [1024][512]
    const float* Wo_b = (const float*)d_in[9];   // [1024]
    float* out = (float*)d_out;

    char* ws = (char*)d_ws;
    float* emb_proj = (float*)ws;                                   // 2048*512 f32 = 4 MiB
    float* Wsw      = (float*)(ws + (size_t)2048 * 512 * 4);        // 512*512 f32 = 1 MiB
    float* hs       = (float*)(ws + (size_t)(2048 * 512 + 512 * 512) * 4); // 64*512*512 f32 = 64 MiB

    // 1) swizzle Wh for the scan kernel
    prep_wsw<<<(512 * 512) / 256, 256, 0, stream>>>(Wh_w, Wsw);

    // 2) emb_proj = emb @ Wx^T + Wx_b + Wh_b   (only 2048 distinct rows!)
    dim3 g1(512 / 64, 2048 / 64);
    gemm_nt_f32<<<g1, 256, 0, stream>>>(emb, Wx_w, emb_proj,
                                        2048, 512, 512, Wx_b, Wh_b, 0);

    // 3) sequential recurrence, gathers emb_proj rows by idx
    ltc_scan<<<BATCH, HID, 0, stream>>>(q, r, emb_proj, Wsw, tau, hs);

    // 4) y = sigmoid(hs @ Wo^T + Wo_b)
    dim3 g2(1024 / 64, 32768 / 64);
    gemm_nt_f32<<<g2, 256, 0, stream>>>(hs, Wo_w, out,
                                        BATCH * SEQ, NUM_C, 512, Wo_b, nullptr, 1);
}